// Round 2
// baseline (156.392 us; speedup 1.0000x reference)
//
#include <hip/hip_runtime.h>
#include <hip/hip_bf16.h>
#include <stdint.h>

typedef __attribute__((ext_vector_type(8))) __bf16 bf16x8;
typedef __attribute__((ext_vector_type(16))) float floatx16;

#if __has_builtin(__builtin_amdgcn_exp2f)
#define EXP2F(x) __builtin_amdgcn_exp2f(x)
#else
#define EXP2F(x) exp2f(x)
#endif

#define GAS __attribute__((address_space(1)))
#define LAS __attribute__((address_space(3)))

// sqrt(2*log2(e)): baked into normalized rows so dot = 2*log2(e)*cos and
// sim = exp2(dot) = exp(cos/0.5) with zero epilogue multiplies.
#define SCALE_SQRT 1.69864359f

// ---------------- prep: int64-probe labels + normalize + zero accumulators ----
__global__ __launch_bounds__(256) void k_prep(const float* __restrict__ x,
                                              const int* __restrict__ raw,
                                              ushort* __restrict__ xb,
                                              int* __restrict__ lab,
                                              float* __restrict__ negs,
                                              float* __restrict__ poss, int N) {
  const int row = (blockIdx.x * 256 + threadIdx.x) >> 6;  // one wave per row
  const int lane = threadIdx.x & 63;
  if (row >= N) return;
  // parallel int64 detection: odd words all zero => labels are int64
  const int probe = raw[2 * lane + 1];
  const bool is64 = (__ballot(probe != 0) == 0ull);
  const float2 v = ((const float2*)(x + (size_t)row * 128))[lane];
  float ss = v.x * v.x + v.y * v.y;
#pragma unroll
  for (int m = 1; m < 64; m <<= 1) ss += __shfl_xor(ss, m, 64);
  const float rn = SCALE_SQRT / fmaxf(sqrtf(ss), 1e-12f);
  __hip_bfloat162 o;
  o.x = __float2bfloat16(v.x * rn);
  o.y = __float2bfloat16(v.y * rn);
  ((__hip_bfloat162*)xb)[row * 64 + lane] = o;
  if (lane == 0) {
    lab[row] = is64 ? raw[2 * row] : raw[row];
    negs[row] = 0.0f;
    poss[row] = 0.0f;
  }
}

// ---------------- main: upper-triangle tiled exp(x x^T/T) row+col sums -------
// 512 blocks; block b: pair p=b>>4 owns strips (p, 63-p) = 65 tiles, chunk
// c=b&15 takes tiles [c*65/16,(c+1)*65/16). Off-diag tile (ti<tj) credits
// rows (ti side) AND cols (tj side, by symmetry). Diag tile: rows only,
// self-diagonal zeroed. LDS XOR-16 swizzle (global-source-permuted).
__global__ __launch_bounds__(256, 2) void k_sim(const ushort* __restrict__ xb,
                                                const int* __restrict__ lab,
                                                float* __restrict__ negs,
                                                float* __restrict__ poss) {
  __shared__ ushort ldsA[128 * 128];
  __shared__ ushort ldsB[128 * 128];
  const int tid = threadIdx.x;
  const int lane = tid & 63;
  const int wv = tid >> 6;
  const int wy = wv >> 1, wx = wv & 1;
  const int l31 = lane & 31, g2 = lane >> 5;
  const int l15 = lane & 15, g4 = lane >> 4;

  const int b = blockIdx.x;
  const int p = b >> 4, c = b & 15;
  const int t0 = (c * 65) >> 4, t1 = ((c + 1) * 65) >> 4;

  float neg[32], pos[32];
  int li[32];
  int curTi = -1;

  // C/D 32x32 layout: col = lane&31, row = (reg&3) + 8*(reg>>2) + 4*(lane>>5)
  auto rowOff = [&](int t) -> int {
    const int reg = t & 15, mi = t >> 4;
    return wy * 64 + mi * 32 + (reg & 3) + 8 * (reg >> 2) + 4 * g2;
  };
  auto flushRows = [&](int ti) {
#pragma unroll
    for (int t = 0; t < 32; ++t) {
      float n = neg[t], q = pos[t];
#pragma unroll
      for (int m = 1; m < 32; m <<= 1) {
        n += __shfl_xor(n, m, 64);
        q += __shfl_xor(q, m, 64);
      }
      if (l31 == 0) {
        const int i = ti * 128 + rowOff(t);
        atomicAdd(&negs[i], n);
        atomicAdd(&poss[i], q);
      }
    }
  };
  auto stage = [&](ushort* lds, const ushort* src) {
#pragma unroll
    for (int it = 0; it < 8; ++it) {
      const int r0 = it * 16 + wv * 4;   // wave-uniform LDS row base (4 rows)
      const int lr = r0 + g4;
      const int kb = l15 ^ (lr & 15);    // XOR-16: source-permuted swizzle
      const ushort* gp = src + (size_t)lr * 128 + kb * 8;
      __builtin_amdgcn_global_load_lds((GAS void*)gp, (LAS void*)&lds[r0 * 128], 16, 0, 0);
    }
  };

  for (int t = t0; t < t1; ++t) {
    int ti, tj;
    if (t < 64 - p) { ti = p; tj = p + t; }
    else            { ti = 63 - p; tj = ti + t - (64 - p); }
    const bool newA = (ti != curTi);

    __syncthreads();  // prior tile's ds_reads complete -> safe to overwrite LDS
    if (newA) stage(ldsA, xb + (size_t)ti * 128 * 128);
    stage(ldsB, xb + (size_t)tj * 128 * 128);
    const int lj0 = lab[tj * 128 + wx * 64 + l31];
    const int lj1 = lab[tj * 128 + wx * 64 + 32 + l31];
    if (newA) {
      if (curTi >= 0) flushRows(curTi);
#pragma unroll
      for (int q = 0; q < 32; ++q) {
        li[q] = lab[ti * 128 + rowOff(q)];
        neg[q] = 0.0f;
        pos[q] = 0.0f;
      }
      curTi = ti;
    }
    __syncthreads();  // staging (vmcnt drain) complete

    floatx16 acc[2][2];
#pragma unroll
    for (int mi = 0; mi < 2; ++mi)
#pragma unroll
      for (int ni = 0; ni < 2; ++ni) acc[mi][ni] = (floatx16)(0.0f);

#pragma unroll
    for (int kt = 0; kt < 8; ++kt) {
      bf16x8 af[2], bfr[2];
#pragma unroll
      for (int mi = 0; mi < 2; ++mi) {
        const int lr = wy * 64 + mi * 32 + l31;   // A fragment: m = lane&31
        const int kb = (kt * 2 + g2) ^ (lr & 15);
        af[mi] = *(const bf16x8*)&ldsA[lr * 128 + kb * 8];
      }
#pragma unroll
      for (int ni = 0; ni < 2; ++ni) {
        const int lr = wx * 64 + ni * 32 + l31;   // B fragment: n = lane&31
        const int kb = (kt * 2 + g2) ^ (lr & 15);
        bfr[ni] = *(const bf16x8*)&ldsB[lr * 128 + kb * 8];
      }
#pragma unroll
      for (int mi = 0; mi < 2; ++mi)
#pragma unroll
        for (int ni = 0; ni < 2; ++ni)
          acc[mi][ni] = __builtin_amdgcn_mfma_f32_32x32x16_bf16(af[mi], bfr[ni],
                                                                acc[mi][ni], 0, 0, 0);
    }

    // ---- epilogue: exp2 + row sums (+ col sums via symmetry, off-diag) ----
    float cn[2] = {0.0f, 0.0f}, cp[2] = {0.0f, 0.0f};
    const bool diag = (ti == tj);
    auto epi = [&](bool DG) {
#pragma unroll
      for (int mi = 0; mi < 2; ++mi) {
#pragma unroll
        for (int ni = 0; ni < 2; ++ni) {
          const int lj = ni ? lj1 : lj0;
#pragma unroll
          for (int reg = 0; reg < 16; ++reg) {
            float e = EXP2F(acc[mi][ni][reg]);
            if (DG) {
              const int ir = wy * 64 + mi * 32 + (reg & 3) + 8 * (reg >> 2) + 4 * g2;
              const int jc = wx * 64 + ni * 32 + l31;
              if (ir == jc) e = 0.0f;  // exclude self-similarity exactly
            }
            const bool match = (li[mi * 16 + reg] == lj);
            const float ep = match ? e : 0.0f;
            neg[mi * 16 + reg] += e;
            pos[mi * 16 + reg] += ep;
            if (!DG) { cn[ni] += e; cp[ni] += ep; }
          }
        }
      }
    };
    if (diag) epi(true); else epi(false);

    if (!diag) {  // flush column sums (rows of strip tj, by symmetry)
#pragma unroll
      for (int ni = 0; ni < 2; ++ni) {
        const float n2 = cn[ni] + __shfl_xor(cn[ni], 32, 64);
        const float p2 = cp[ni] + __shfl_xor(cp[ni], 32, 64);
        if (g2 == 0) {
          const int j = tj * 128 + wx * 64 + ni * 32 + l31;
          atomicAdd(&negs[j], n2);
          atomicAdd(&poss[j], p2);
        }
      }
    }
  }
  flushRows(curTi);
}

// ---------------- finalize: hist + mean(-log(pos/cnt/neg)) -------------------
__global__ __launch_bounds__(1024) void k_final(const float* __restrict__ negs,
                                                const float* __restrict__ poss,
                                                const int* __restrict__ lab,
                                                float* __restrict__ out, int N) {
  __shared__ int h[64];
  if (threadIdx.x < 64) h[threadIdx.x] = 0;
  __syncthreads();
  for (int i = threadIdx.x; i < N; i += 1024) atomicAdd(&h[lab[i] & 63], 1);
  __syncthreads();
  double s = 0.0;
  for (int i = threadIdx.x; i < N; i += 1024) {
    const float cnt = (float)(h[lab[i] & 63] - 1);
    s += (double)logf(negs[i] * cnt / poss[i]);
  }
#pragma unroll
  for (int m = 1; m < 64; m <<= 1) s += __shfl_xor(s, m, 64);
  __shared__ double wsum[16];
  if ((threadIdx.x & 63) == 0) wsum[threadIdx.x >> 6] = s;
  __syncthreads();
  if (threadIdx.x == 0) {
    double tot = 0.0;
    for (int w = 0; w < 16; ++w) tot += wsum[w];
    out[0] = (float)(tot / (double)N);
  }
}

extern "C" void kernel_launch(void* const* d_in, const int* in_sizes, int n_in,
                              void* d_out, int out_size, void* d_ws, size_t ws_size,
                              hipStream_t stream) {
  const float* x = (const float*)d_in[0];
  const int* raw_label = (const int*)d_in[1];
  const int N = in_sizes[1];  // 8192
  char* ws = (char*)d_ws;
  ushort* xb = (ushort*)ws;                          // N*128 bf16 = 2 MB
  float* negs = (float*)(ws + (size_t)N * 128 * 2);  // N f32
  float* poss = negs + N;                            // N f32
  int* lab = (int*)(poss + N);                       // N ints
  float* out = (float*)d_out;

  k_prep<<<dim3(N / 4), dim3(256), 0, stream>>>(x, raw_label, xb, lab, negs, poss, N);
  k_sim<<<dim3(512), dim3(256), 0, stream>>>(xb, lab, negs, poss);
  k_final<<<dim3(1), dim3(1024), 0, stream>>>(negs, poss, lab, out, N);
}

// Round 3
// 101.660 us; speedup vs baseline: 1.5384x; 1.5384x over previous
//
#include <hip/hip_runtime.h>
#include <hip/hip_bf16.h>
#include <stdint.h>

typedef __attribute__((ext_vector_type(8))) __bf16 bf16x8;
typedef __attribute__((ext_vector_type(16))) float floatx16;

#if __has_builtin(__builtin_amdgcn_exp2f)
#define EXP2F(x) __builtin_amdgcn_exp2f(x)
#else
#define EXP2F(x) exp2f(x)
#endif

#define GAS __attribute__((address_space(1)))
#define LAS __attribute__((address_space(3)))

// sqrt(2*log2(e)): baked into normalized rows so dot = 2*log2(e)*cos and
// sim = exp2(dot) = exp(cos/0.5) with zero epilogue multiplies.
#define SCALE_SQRT 1.69864359f
#define JCH 8  // j-chunks; grid = 64 strips x 8 chunks = 512 blocks = 2/CU

// ---------------- prep: int64-probe labels + normalize -----------------------
__global__ __launch_bounds__(256) void k_prep(const float* __restrict__ x,
                                              const int* __restrict__ raw,
                                              ushort* __restrict__ xb,
                                              int* __restrict__ lab, int N) {
  const int row = (blockIdx.x * 256 + threadIdx.x) >> 6;  // one wave per row
  const int lane = threadIdx.x & 63;
  if (row >= N) return;
  // parallel int64 detection: odd words all zero => labels are int64
  const int probe = raw[2 * lane + 1];
  const bool is64 = (__ballot(probe != 0) == 0ull);
  const float2 v = ((const float2*)(x + (size_t)row * 128))[lane];
  float ss = v.x * v.x + v.y * v.y;
#pragma unroll
  for (int m = 1; m < 64; m <<= 1) ss += __shfl_xor(ss, m, 64);
  const float rn = SCALE_SQRT / fmaxf(sqrtf(ss), 1e-12f);
  __hip_bfloat162 o;
  o.x = __float2bfloat16(v.x * rn);
  o.y = __float2bfloat16(v.y * rn);
  ((__hip_bfloat162*)xb)[row * 64 + lane] = o;
  if (lane == 0) lab[row] = is64 ? raw[2 * row] : raw[row];
}

// ---------------- main: full-matrix tiled exp(x x^T/T) row sums --------------
// grid (JCH, N/128). Block: 256 thr, strip of 128 i-rows, 16 j-tiles of 64 cols.
// LDS: A 32 KB (whole strip, staged once) + B 2x16 KB double-buffered.
// Per tile: prefetch next B -> compute (8 kt x 2 mfma/wave) -> epilogue -> barrier.
// NO atomics: per-chunk row partials go to pneg/ppos[chunk][row] as plain stores.
__global__ __launch_bounds__(256, 2) void k_sim(const ushort* __restrict__ xb,
                                                const int* __restrict__ lab,
                                                float* __restrict__ pneg,
                                                float* __restrict__ ppos,
                                                int N, int jpb) {
  __shared__ ushort ldsA[128 * 128];     // 32 KB
  __shared__ ushort ldsB[2][64 * 128];   // 2 x 16 KB
  const int tid = threadIdx.x;
  const int lane = tid & 63;
  const int wv = tid >> 6;
  const int wy = wv >> 1, wx = wv & 1;   // wave covers rows wy*64+[0,64), cols wx*32+[0,32)
  const int l31 = lane & 31, g2 = lane >> 5;
  const int l15 = lane & 15, g4 = lane >> 4;
  const int i0 = blockIdx.y * 128;
  const int c = blockIdx.x;
  const int jt0 = c * jpb;

  // C/D 32x32 layout: col = lane&31, row = (reg&3) + 8*(reg>>2) + 4*(lane>>5)
  auto rowOff = [&](int t) -> int {
    const int reg = t & 15, mi = t >> 4;
    return wy * 64 + mi * 32 + (reg & 3) + 8 * (reg >> 2) + 4 * g2;
  };

  // ---- stage A strip (32 KB, once), XOR-16 source-permuted swizzle ----
#pragma unroll
  for (int it = 0; it < 8; ++it) {
    const int r0 = it * 16 + wv * 4;     // wave-uniform LDS row base
    const int lr = r0 + g4;
    const int kb = l15 ^ (lr & 15);
    const ushort* gp = xb + (size_t)(i0 + lr) * 128 + kb * 8;
    __builtin_amdgcn_global_load_lds((GAS void*)gp, (LAS void*)&ldsA[r0 * 128], 16, 0, 0);
  }
  // ---- stage first B tile ----
  {
    const int j0 = jt0 * 64;
#pragma unroll
    for (int it = 0; it < 4; ++it) {
      const int r0 = it * 16 + wv * 4;
      const int lr = r0 + g4;
      const int kb = l15 ^ (lr & 15);
      const ushort* gp = xb + (size_t)(j0 + lr) * 128 + kb * 8;
      __builtin_amdgcn_global_load_lds((GAS void*)gp, (LAS void*)&ldsB[0][r0 * 128], 16, 0, 0);
    }
  }

  // per-lane row labels + accumulators (overlap with staging)
  int li[32];
  float neg[32], pos[32];
#pragma unroll
  for (int t = 0; t < 32; ++t) {
    li[t] = lab[i0 + rowOff(t)];
    neg[t] = 0.0f;
    pos[t] = 0.0f;
  }
  __syncthreads();  // A + B0 staged (vmcnt drained per wave at barrier)

  for (int t = 0; t < jpb; ++t) {
    const int j0 = (jt0 + t) * 64;
    const int buf = t & 1;
    if (t + 1 < jpb) {  // prefetch next B into other buffer; lands during compute
      const int jn = j0 + 64;
#pragma unroll
      for (int it = 0; it < 4; ++it) {
        const int r0 = it * 16 + wv * 4;
        const int lr = r0 + g4;
        const int kb = l15 ^ (lr & 15);
        const ushort* gp = xb + (size_t)(jn + lr) * 128 + kb * 8;
        __builtin_amdgcn_global_load_lds((GAS void*)gp, (LAS void*)&ldsB[buf ^ 1][r0 * 128], 16, 0, 0);
      }
    }
    const int lj = lab[j0 + wx * 32 + l31];  // column label (per lane)

    floatx16 acc[2];
    acc[0] = (floatx16)(0.0f);
    acc[1] = (floatx16)(0.0f);
#pragma unroll
    for (int kt = 0; kt < 8; ++kt) {
      const int brow = wx * 32 + l31;
      const int bkb = (kt * 2 + g2) ^ (brow & 15);
      const bf16x8 bfr = *(const bf16x8*)&ldsB[buf][brow * 128 + bkb * 8];
#pragma unroll
      for (int mi = 0; mi < 2; ++mi) {
        const int arow = wy * 64 + mi * 32 + l31;
        const int akb = (kt * 2 + g2) ^ (arow & 15);
        const bf16x8 af = *(const bf16x8*)&ldsA[arow * 128 + akb * 8];
        acc[mi] = __builtin_amdgcn_mfma_f32_32x32x16_bf16(af, bfr, acc[mi], 0, 0, 0);
      }
    }

    // ---- epilogue: exp2, diag-skip, row accumulation (registers only) ----
    const int dlt = j0 - i0;                  // tile touches diagonal iff dlt in {0,64}
    const bool diag = ((unsigned)dlt < 128u);
    const int jc = wx * 32 + l31 + dlt;       // global-diag test: ir == jc
    auto epi = [&](bool DG) {
#pragma unroll
      for (int mi = 0; mi < 2; ++mi) {
#pragma unroll
        for (int reg = 0; reg < 16; ++reg) {
          float e = EXP2F(acc[mi][reg]);
          if (DG) {
            const int ir = wy * 64 + mi * 32 + (reg & 3) + 8 * (reg >> 2) + 4 * g2;
            if (ir == jc) e = 0.0f;           // exclude self-similarity exactly
          }
          neg[mi * 16 + reg] += e;
          pos[mi * 16 + reg] += (li[mi * 16 + reg] == lj) ? e : 0.0f;
        }
      }
    };
    if (diag) epi(true); else epi(false);
    __syncthreads();  // all reads of buf done; prefetch(t+1) already drained
  }

  // ---- flush: wave-reduce over 32 cols, combine wx halves in LDS, store ----
  float* fl = (float*)ldsB;  // [row][neg|pos][wx] = 128*2*2 floats (2 KB)
#pragma unroll
  for (int t = 0; t < 32; ++t) {
    float n = neg[t], p = pos[t];
#pragma unroll
    for (int m = 1; m < 32; m <<= 1) {
      n += __shfl_xor(n, m, 64);
      p += __shfl_xor(p, m, 64);
    }
    if (l31 == 0) {
      const int r = rowOff(t);
      fl[(r * 2 + 0) * 2 + wx] = n;
      fl[(r * 2 + 1) * 2 + wx] = p;
    }
  }
  __syncthreads();
  if (tid < 128) {
    const int r = tid;
    pneg[(size_t)c * N + i0 + r] = fl[(r * 2 + 0) * 2] + fl[(r * 2 + 0) * 2 + 1];
    ppos[(size_t)c * N + i0 + r] = fl[(r * 2 + 1) * 2] + fl[(r * 2 + 1) * 2 + 1];
  }
}

// ---------------- finalize: hist + sum partials + mean(log(neg*cnt/pos)) -----
__global__ __launch_bounds__(1024) void k_final(const float* __restrict__ pneg,
                                                const float* __restrict__ ppos,
                                                const int* __restrict__ lab,
                                                float* __restrict__ out, int N) {
  __shared__ int h[64];
  if (threadIdx.x < 64) h[threadIdx.x] = 0;
  __syncthreads();
  for (int i = threadIdx.x; i < N; i += 1024) atomicAdd(&h[lab[i] & 63], 1);
  __syncthreads();
  double s = 0.0;
  for (int i = threadIdx.x; i < N; i += 1024) {
    float n = 0.0f, p = 0.0f;
#pragma unroll
    for (int c = 0; c < JCH; ++c) {
      n += pneg[(size_t)c * N + i];
      p += ppos[(size_t)c * N + i];
    }
    const float cnt = (float)(h[lab[i] & 63] - 1);
    s += (double)logf(n * cnt / p);
  }
#pragma unroll
  for (int m = 1; m < 64; m <<= 1) s += __shfl_xor(s, m, 64);
  __shared__ double wsum[16];
  if ((threadIdx.x & 63) == 0) wsum[threadIdx.x >> 6] = s;
  __syncthreads();
  if (threadIdx.x == 0) {
    double tot = 0.0;
    for (int w = 0; w < 16; ++w) tot += wsum[w];
    out[0] = (float)(tot / (double)N);
  }
}

extern "C" void kernel_launch(void* const* d_in, const int* in_sizes, int n_in,
                              void* d_out, int out_size, void* d_ws, size_t ws_size,
                              hipStream_t stream) {
  const float* x = (const float*)d_in[0];
  const int* raw_label = (const int*)d_in[1];
  const int N = in_sizes[1];  // 8192
  char* ws = (char*)d_ws;
  ushort* xb = (ushort*)ws;                          // N*128 bf16 = 2 MB
  float* pneg = (float*)(ws + (size_t)N * 128 * 2);  // JCH*N f32 = 256 KB
  float* ppos = pneg + (size_t)JCH * N;              // JCH*N f32 = 256 KB
  int* lab = (int*)(ppos + (size_t)JCH * N);         // N ints
  float* out = (float*)d_out;

  const int jpb = (N / 64) / JCH;  // 16 j-tiles per block

  k_prep<<<dim3(N / 4), dim3(256), 0, stream>>>(x, raw_label, xb, lab, N);
  k_sim<<<dim3(JCH, N / 128), dim3(256), 0, stream>>>(xb, lab, pneg, ppos, N, jpb);
  k_final<<<dim3(1), dim3(1024), 0, stream>>>(pneg, ppos, lab, out, N);
}